// Round 8
// baseline (34.174 us; speedup 1.0000x reference)
//
#include <hip/hip_runtime.h>
#include <math.h>

#define HID 512
#define EMB 1024
#define N1 1536
#define N2 256
#define P2S (128 * 256)

typedef __attribute__((ext_vector_type(8))) __bf16 bf16x8;
typedef __attribute__((ext_vector_type(4))) __bf16 bf16x4;
typedef __attribute__((ext_vector_type(4))) float fx4;

// ---------------- ws layout (bytes) ----------------
#define OFF_ABUF 0            // [384][1024] bf16 = 786432
#define OFF_TWB  786432       // [512][1024] bf16 = 1048576
#define OFF_W1B  1835008      // [256][1536] bf16 = 786432
#define OFF_INPB 2621440      // [128][1536] bf16 = 393216
#define OFF_P2   3014656      // [4][128][256] f32 = 524288
#define OFF_UIDX 3538944      // [128] i32

__device__ __forceinline__ fx4 mfma16(bf16x8 a, bf16x8 b, fx4 c) {
    return __builtin_amdgcn_mfma_f32_16x16x32_bf16(a, b, c, 0, 0, 0);
}

// ========== kPrep: all conversions + gather + uidx, maximally wide ==========
// blocks 0..383: Abuf row; 384..895: twb row; 896..1151: w1b row; 1152..: scan.
__global__ __launch_bounds__(256)
void kPrep(const int* __restrict__ sample, const int* __restrict__ gb, int n_nodes,
           const float* __restrict__ tweet_emb, const float* __restrict__ desc_emb,
           const float* __restrict__ t_w, const float* __restrict__ w1,
           __bf16* __restrict__ Abuf, __bf16* __restrict__ twb,
           __bf16* __restrict__ w1b, int* __restrict__ uidx)
{
    const int blk = blockIdx.x;
    const int t   = threadIdx.x;

    if (blk < 384) {
        const int s = blk >> 7, b = blk & 127;
        const int id = sample[b * 3 + s];
        const float* src = (s == 1) ? (tweet_emb + (size_t)id * EMB)
                                    : (desc_emb + (size_t)id * EMB);
        float4 v = *(const float4*)(src + t * 4);
        bf16x4 o = {(__bf16)v.x, (__bf16)v.y, (__bf16)v.z, (__bf16)v.w};
        *(bf16x4*)(Abuf + (size_t)blk * EMB + t * 4) = o;
    } else if (blk < 896) {
        const int r = blk - 384;
        float4 v = *(const float4*)(t_w + (size_t)r * EMB + t * 4);
        bf16x4 o = {(__bf16)v.x, (__bf16)v.y, (__bf16)v.z, (__bf16)v.w};
        *(bf16x4*)(twb + (size_t)r * EMB + t * 4) = o;
    } else if (blk < 1152) {
        const int r = blk - 896;
        #pragma unroll
        for (int i = t; i < 384; i += 256) {
            float4 v = *(const float4*)(w1 + (size_t)r * N1 + i * 4);
            bf16x4 o = {(__bf16)v.x, (__bf16)v.y, (__bf16)v.z, (__bf16)v.w};
            *(bf16x4*)(w1b + (size_t)r * N1 + i * 4) = o;
        }
    } else {
        const int n = (blk - 1152) * 256 + t;
        if (n < n_nodes) {
            const int g = gb[n];
            if (n == 0 || gb[n - 1] != g) uidx[g] = n;
        }
    }
}

// ========== kG1: GEMM1, full K=1024 staged in LDS, ONE barrier ==========
// grid (16 n-tiles, 12 m-tiles) = 192 blocks, 256 thr (4 waves, 16x16 out each).
__global__ __launch_bounds__(256, 1)
void kG1(const __bf16* __restrict__ Abuf, const __bf16* __restrict__ twb,
         const float* __restrict__ t_b, const float* __restrict__ p_feature,
         const int* __restrict__ uidx, __bf16* __restrict__ inp_bf)
{
    const int n0 = blockIdx.x * 32;
    const int m0 = blockIdx.y * 32;
    const int t  = threadIdx.x;
    const int wid = t >> 6, l = t & 63;
    const int mbase = (wid >> 1) * 16, nbase = (wid & 1) * 16;

    __shared__ __bf16 Alds[32 * 1024];   // 64 KB
    __shared__ __bf16 Blds[32 * 1024];   // 64 KB

    bf16x8 areg[16], breg[16];
    #pragma unroll
    for (int i = 0; i < 16; ++i) {
        const int c = i * 256 + t;                 // granule index 0..4095
        const int row = c >> 7, g = c & 127;
        areg[i] = *(const bf16x8*)(Abuf + (size_t)(m0 + row) * EMB + g * 8);
        breg[i] = *(const bf16x8*)(twb  + (size_t)(n0 + row) * EMB + g * 8);
    }
    #pragma unroll
    for (int i = 0; i < 16; ++i) {
        const int c = i * 256 + t;
        const int row = c >> 7, g = c & 127;
        const int gp = g ^ (row & 7);              // bank-quad swizzle
        *(bf16x8*)(Alds + row * 1024 + gp * 8) = areg[i];
        *(bf16x8*)(Blds + row * 1024 + gp * 8) = breg[i];
    }
    __syncthreads();

    fx4 acc0 = {}, acc1 = {};
    const int fr = l & 15, fq = l >> 4;
    const __bf16* Ab = Alds + (mbase + fr) * 1024;
    const __bf16* Bb = Blds + (nbase + fr) * 1024;
    const int ax = (mbase + fr) & 7, bx = (nbase + fr) & 7;
    #pragma unroll
    for (int s = 0; s < 32; s += 2) {
        bf16x8 a0 = *(const bf16x8*)(Ab + ((s * 4 + fq) ^ ax) * 8);
        bf16x8 b0 = *(const bf16x8*)(Bb + ((s * 4 + fq) ^ bx) * 8);
        acc0 = mfma16(a0, b0, acc0);
        bf16x8 a1 = *(const bf16x8*)(Ab + (((s + 1) * 4 + fq) ^ ax) * 8);
        bf16x8 b1 = *(const bf16x8*)(Bb + (((s + 1) * 4 + fq) ^ bx) * 8);
        acc1 = mfma16(a1, b1, acc1);
    }

    const int sid  = m0 >> 7;                      // 0,1,2
    const int col  = n0 + nbase + fr;
    const int row0 = m0 + mbase + fq * 4;
    const float tb = t_b[col];
    #pragma unroll
    for (int j = 0; j < 4; ++j) {
        const int r = row0 + j;
        float v = acc0[j] + acc1[j] + tb;
        if (sid != 1) {
            const int node = uidx[r & 127] + ((sid == 2) ? 1 : 0);
            v += p_feature[(size_t)node * HID + col];
        }
        inp_bf[(size_t)(r & 127) * N1 + sid * HID + col] = (__bf16)v;
    }
}

// ========== kG2: GEMM2, K=384 quarters in LDS, ONE barrier, all-bf16 ==========
// part2[ks][b][col] = inp_bf[b][ks*384:+384] . w1b[col][ks*384:+384]
// grid (8 n-tiles, 4 m-tiles, 4 ks) = 128 blocks; LDS 48 KB -> 2 blocks/CU.
__global__ __launch_bounds__(256)
void kG2(const __bf16* __restrict__ inp_bf, const __bf16* __restrict__ w1b,
         float* __restrict__ part2)
{
    const int n0 = blockIdx.x * 32;
    const int m0 = blockIdx.y * 32;
    const int ks = blockIdx.z;
    const int t  = threadIdx.x;
    const int wid = t >> 6, l = t & 63;
    const int mbase = (wid >> 1) * 16, nbase = (wid & 1) * 16;

    __shared__ __bf16 Alds[32 * 384];    // 24 KB
    __shared__ __bf16 Blds[32 * 384];    // 24 KB

    // stage: 32 rows x 48 granules = 1536 granules per matrix; 6 per thread
    bf16x8 areg[6], breg[6];
    #pragma unroll
    for (int i = 0; i < 6; ++i) {
        const int c = i * 256 + t;                 // 0..1535
        const int row = c / 48, g = c % 48;
        areg[i] = *(const bf16x8*)(inp_bf + (size_t)(m0 + row) * N1 + ks * 384 + g * 8);
        breg[i] = *(const bf16x8*)(w1b   + (size_t)(n0 + row) * N1 + ks * 384 + g * 8);
    }
    #pragma unroll
    for (int i = 0; i < 6; ++i) {
        const int c = i * 256 + t;
        const int row = c / 48, g = c % 48;
        const int gp = g ^ (row & 7);
        *(bf16x8*)(Alds + row * 384 + gp * 8) = areg[i];
        *(bf16x8*)(Blds + row * 384 + gp * 8) = breg[i];
    }
    __syncthreads();

    fx4 acc0 = {}, acc1 = {};
    const int fr = l & 15, fq = l >> 4;
    const __bf16* Ab = Alds + (mbase + fr) * 384;
    const __bf16* Bb = Blds + (nbase + fr) * 384;
    const int ax = (mbase + fr) & 7, bx = (nbase + fr) & 7;
    #pragma unroll
    for (int s = 0; s < 12; s += 2) {
        bf16x8 a0 = *(const bf16x8*)(Ab + ((s * 4 + fq) ^ ax) * 8);
        bf16x8 b0 = *(const bf16x8*)(Bb + ((s * 4 + fq) ^ bx) * 8);
        acc0 = mfma16(a0, b0, acc0);
        bf16x8 a1 = *(const bf16x8*)(Ab + (((s + 1) * 4 + fq) ^ ax) * 8);
        bf16x8 b1 = *(const bf16x8*)(Bb + (((s + 1) * 4 + fq) ^ bx) * 8);
        acc1 = mfma16(a1, b1, acc1);
    }

    float* dst = part2 + (size_t)ks * P2S;
    const int col  = n0 + nbase + fr;
    const int row0 = m0 + mbase + fq * 4;
    #pragma unroll
    for (int j = 0; j < 4; ++j)
        dst[(size_t)(row0 + j) * N2 + col] = acc0[j] + acc1[j];
}

// ========== kEF: combine 4 partials + redundant BN stats + output ==========
// 16 blocks x 256; thread t computes column-t stats (same f32 add order as output).
__global__ __launch_bounds__(256)
void kEF(const float* __restrict__ part2, const float* __restrict__ b1,
         const float* __restrict__ gamma, const float* __restrict__ beta,
         const float* __restrict__ w2, const float* __restrict__ b2,
         float* __restrict__ out)
{
    __shared__ float s_scale[256];
    __shared__ float s_shift[256];
    const int t = threadIdx.x;

    const float bias = b1[t];
    float sum = 0.f, sq = 0.f;
    #pragma unroll 4
    for (int r = 0; r < 128; ++r) {
        float v = (((part2[r * N2 + t] + part2[P2S + r * N2 + t])
                  + part2[2 * P2S + r * N2 + t]) + part2[3 * P2S + r * N2 + t]) + bias;
        sum += v;
        sq  += v * v;
    }
    const float mu  = sum * (1.0f / 128.0f);
    const float var = sq * (1.0f / 128.0f) - mu * mu;   // biased batch var
    const float rs  = rsqrtf(var + 1e-5f);
    const float sc  = gamma[t] * rs;
    s_scale[t] = sc;
    s_shift[t] = beta[t] - mu * sc;
    __syncthreads();

    const int wv = t >> 6, l = t & 63;
    #pragma unroll
    for (int rr = 0; rr < 2; ++rr) {
        const int b = blockIdx.x * 8 + wv * 2 + rr;
        float acc = 0.f;
        #pragma unroll
        for (int i = 0; i < 4; ++i) {
            const int j = l + i * 64;
            float v = (((part2[b * N2 + j] + part2[P2S + b * N2 + j])
                      + part2[2 * P2S + b * N2 + j]) + part2[3 * P2S + b * N2 + j]) + b1[j];
            float x = v * s_scale[j] + s_shift[j];
            x = fmaxf(x, 0.f);
            acc += x * w2[j];
        }
        #pragma unroll
        for (int off = 32; off; off >>= 1) acc += __shfl_xor(acc, off);
        if (l == 0) out[b] = 1.0f / (1.0f + expf(-(acc + b2[0])));
    }
}

extern "C" void kernel_launch(void* const* d_in, const int* in_sizes, int n_in,
                              void* d_out, int out_size, void* d_ws, size_t ws_size,
                              hipStream_t stream) {
    const int*   sample    = (const int*)  d_in[0];
    const int*   gb        = (const int*)  d_in[1];
    const float* p_feature = (const float*)d_in[2];
    const float* tweet_emb = (const float*)d_in[3];
    const float* desc_emb  = (const float*)d_in[4];
    const float* t_w       = (const float*)d_in[5];
    const float* t_b       = (const float*)d_in[6];
    const float* w1        = (const float*)d_in[7];
    const float* b1        = (const float*)d_in[8];
    const float* gamma     = (const float*)d_in[9];
    const float* beta      = (const float*)d_in[10];
    const float* w2        = (const float*)d_in[11];
    const float* b2        = (const float*)d_in[12];
    float* out = (float*)d_out;

    char* ws = (char*)d_ws;
    __bf16* Abuf   = (__bf16*)(ws + OFF_ABUF);
    __bf16* twb    = (__bf16*)(ws + OFF_TWB);
    __bf16* w1b    = (__bf16*)(ws + OFF_W1B);
    __bf16* inp_bf = (__bf16*)(ws + OFF_INPB);
    float*  part2  = (float*)(ws + OFF_P2);
    int*    uidx   = (int*)  (ws + OFF_UIDX);

    const int n_nodes = in_sizes[1];
    const int scatter_blocks = (n_nodes + 255) / 256;

    kPrep<<<1152 + scatter_blocks, 256, 0, stream>>>(sample, gb, n_nodes,
        tweet_emb, desc_emb, t_w, w1, Abuf, twb, w1b, uidx);
    kG1<<<dim3(16, 12), 256, 0, stream>>>(Abuf, twb, t_b, p_feature, uidx, inp_bf);
    kG2<<<dim3(8, 4, 4), 256, 0, stream>>>(inp_bf, w1b, part2);
    kEF<<<16, 256, 0, stream>>>(part2, b1, gamma, beta, w2, b2, out);
}

// Round 9
// 32.305 us; speedup vs baseline: 1.0578x; 1.0578x over previous
//
#include <hip/hip_runtime.h>
#include <math.h>

#define BB 128
#define HID 512
#define EMB 1024
#define N1 1536
#define N2 256
#define P2S (128 * 256)

typedef __attribute__((ext_vector_type(8))) __bf16 bf16x8;
typedef __attribute__((ext_vector_type(4))) __bf16 bf16x4;
typedef __attribute__((ext_vector_type(4))) float fx4;

// ---------------- ws layout (bytes) ----------------
#define OFF_ABUF 0            // [384][1024] bf16   = 786432
#define OFF_TWB  786432       // [512][1024] bf16   = 1048576
#define OFF_W1B  1835008      // [256][1536] bf16   = 786432
#define OFF_INPB 2621440      // [128][1536] bf16   = 393216 (b-major)
#define OFF_P1   3014656      // [4][384][512] f32  = 3145728
#define OFF_P2   6160384      // [4][128][256] f32  = 524288
#define OFF_UIDX 6684672      // [128] i32

__device__ __forceinline__ fx4 mfma16(bf16x8 a, bf16x8 b, fx4 c) {
    return __builtin_amdgcn_mfma_f32_16x16x32_bf16(a, b, c, 0, 0, 0);
}

// LDS tile [64 rows][64 k] bf16; 16B granule g of row r -> physical g ^ (r&7).
__device__ __forceinline__ int lds_idx64(int row, int g) {
    return row * 64 + ((g ^ (row & 7)) * 8);
}

// ========== kA: gather + f32->bf16 convert + u_idx scatter (R2 verbatim) ======
// blocks 0..383: Abuf row; 384..895: twb row; 896..1151: w1b row; 1152..: scan.
__global__ __launch_bounds__(256)
void kA_prep(const int* __restrict__ sample, const int* __restrict__ gb, int n_nodes,
             const float* __restrict__ tweet_emb, const float* __restrict__ desc_emb,
             const float* __restrict__ t_w, const float* __restrict__ w1,
             __bf16* __restrict__ Abuf, __bf16* __restrict__ twb,
             __bf16* __restrict__ w1b, int* __restrict__ uidx)
{
    const int blk = blockIdx.x;
    const int t   = threadIdx.x;

    if (blk < 384) {
        const int s = blk >> 7, b = blk & 127;
        const int id = sample[b * 3 + s];
        const float* src = (s == 1) ? (tweet_emb + (size_t)id * EMB)
                                    : (desc_emb + (size_t)id * EMB);
        float4 v = *(const float4*)(src + t * 4);
        bf16x4 o = {(__bf16)v.x, (__bf16)v.y, (__bf16)v.z, (__bf16)v.w};
        *(bf16x4*)(Abuf + (size_t)blk * EMB + t * 4) = o;
    } else if (blk < 896) {
        const int r = blk - 384;
        float4 v = *(const float4*)(t_w + (size_t)r * EMB + t * 4);
        bf16x4 o = {(__bf16)v.x, (__bf16)v.y, (__bf16)v.z, (__bf16)v.w};
        *(bf16x4*)(twb + (size_t)r * EMB + t * 4) = o;
    } else if (blk < 1152) {
        const int r = blk - 896;
        for (int i = t; i < 384; i += 256) {
            float4 v = *(const float4*)(w1 + (size_t)r * N1 + i * 4);
            bf16x4 o = {(__bf16)v.x, (__bf16)v.y, (__bf16)v.z, (__bf16)v.w};
            *(bf16x4*)(w1b + (size_t)r * N1 + i * 4) = o;
        }
    } else {
        const int n = (blk - 1152) * 256 + t;
        if (n < n_nodes) {
            const int g = gb[n];
            if (n == 0 || gb[n - 1] != g) uidx[g] = n;
        }
    }
}

// ========== kB: GEMM1 (R2 verbatim): part1[ks][m][n], 64x64 tiles, splitK=4 ====
// grid (8 n-tiles, 6 m-tiles, 4 ks) = 192 blocks, 256 thr (4 waves, 32x32 each).
__global__ __launch_bounds__(256)
void kB_gemm1(const __bf16* __restrict__ Abuf, const __bf16* __restrict__ twb,
              float* __restrict__ part1)
{
    const int n0 = blockIdx.x * 64;
    const int m0 = blockIdx.y * 64;
    const int ks = blockIdx.z;
    const int t  = threadIdx.x;
    const int wid = t >> 6, l = t & 63;
    const int mbase = (wid >> 1) * 32, nbase = (wid & 1) * 32;

    __shared__ __bf16 Alds[64 * 64];
    __shared__ __bf16 Blds[64 * 64];

    const int srow = t >> 2;          // staging row 0..63
    const int g0   = (t & 3) * 2;     // granule pair

    fx4 acc[2][2] = {};

    bf16x8 av0, av1, bv0, bv1;
    {
        const int k0 = ks * 256;
        const __bf16* ap = Abuf + (size_t)(m0 + srow) * EMB + k0 + g0 * 8;
        const __bf16* bp = twb  + (size_t)(n0 + srow) * EMB + k0 + g0 * 8;
        av0 = *(const bf16x8*)ap; av1 = *(const bf16x8*)(ap + 8);
        bv0 = *(const bf16x8*)bp; bv1 = *(const bf16x8*)(bp + 8);
    }

    for (int kt = 0; kt < 4; ++kt) {
        __syncthreads();
        *(bf16x8*)&Alds[lds_idx64(srow, g0)]     = av0;
        *(bf16x8*)&Alds[lds_idx64(srow, g0 + 1)] = av1;
        *(bf16x8*)&Blds[lds_idx64(srow, g0)]     = bv0;
        *(bf16x8*)&Blds[lds_idx64(srow, g0 + 1)] = bv1;
        __syncthreads();

        if (kt < 3) {
            const int k0 = ks * 256 + (kt + 1) * 64;
            const __bf16* ap = Abuf + (size_t)(m0 + srow) * EMB + k0 + g0 * 8;
            const __bf16* bp = twb  + (size_t)(n0 + srow) * EMB + k0 + g0 * 8;
            av0 = *(const bf16x8*)ap; av1 = *(const bf16x8*)(ap + 8);
            bv0 = *(const bf16x8*)bp; bv1 = *(const bf16x8*)(bp + 8);
        }

        #pragma unroll
        for (int kq = 0; kq < 2; ++kq) {
            const int g = kq * 4 + (l >> 4);
            bf16x8 a0 = *(const bf16x8*)&Alds[lds_idx64(mbase +      (l & 15), g)];
            bf16x8 a1 = *(const bf16x8*)&Alds[lds_idx64(mbase + 16 + (l & 15), g)];
            bf16x8 b0 = *(const bf16x8*)&Blds[lds_idx64(nbase +      (l & 15), g)];
            bf16x8 b1 = *(const bf16x8*)&Blds[lds_idx64(nbase + 16 + (l & 15), g)];
            acc[0][0] = mfma16(a0, b0, acc[0][0]);
            acc[0][1] = mfma16(a0, b1, acc[0][1]);
            acc[1][0] = mfma16(a1, b0, acc[1][0]);
            acc[1][1] = mfma16(a1, b1, acc[1][1]);
        }
    }

    float* dst = part1 + (size_t)ks * (384 * 512);
    #pragma unroll
    for (int mi = 0; mi < 2; ++mi)
        #pragma unroll
        for (int ni = 0; ni < 2; ++ni) {
            const int row = m0 + mbase + mi * 16 + (l >> 4) * 4;
            const int col = n0 + nbase + ni * 16 + (l & 15);
            #pragma unroll
            for (int j = 0; j < 4; ++j)
                dst[(size_t)(row + j) * 512 + col] = acc[mi][ni][j];
        }
}

// ========== kC: combine partials + t_b + p_feature -> inp_bf (b-major) ========
// grid 192 x 256: block = 2 rows of logical [384][512].
__global__ __launch_bounds__(256)
void kC_comb1(const float* __restrict__ part1, const float* __restrict__ t_b,
              const float* __restrict__ p_feature, const int* __restrict__ uidx,
              __bf16* __restrict__ inp_bf)
{
    const int t = threadIdx.x;
    const int m = blockIdx.x * 2 + (t >> 7);
    const int j0 = (t & 127) * 4;
    const int s = m >> 7, b = m & 127;

    float4 v = *(const float4*)(part1 + (size_t)m * 512 + j0);
    #pragma unroll
    for (int p = 1; p < 4; ++p) {
        float4 q = *(const float4*)(part1 + (size_t)p * (384 * 512) + (size_t)m * 512 + j0);
        v.x += q.x; v.y += q.y; v.z += q.z; v.w += q.w;
    }
    float4 tb = *(const float4*)(t_b + j0);
    v.x += tb.x; v.y += tb.y; v.z += tb.z; v.w += tb.w;
    if (s != 1) {
        const int node = (s == 0) ? uidx[b] : (uidx[b] + 1);
        float4 pf = *(const float4*)(p_feature + (size_t)node * HID + j0);
        v.x += pf.x; v.y += pf.y; v.z += pf.z; v.w += pf.w;
    }
    bf16x4 o = {(__bf16)v.x, (__bf16)v.y, (__bf16)v.z, (__bf16)v.w};
    *(bf16x4*)(inp_bf + (size_t)b * N1 + s * HID + j0) = o;
}

// ========== kG2: GEMM2, K=384 quarters in LDS, ONE barrier, all-bf16 ==========
// part2[ks][b][col] = inp_bf[b][ks*384:+384] . w1b[col][ks*384:+384]
// grid (8 n-tiles, 4 m-tiles, 4 ks) = 128 blocks, 256 thr (4 waves, 16x16 out).
__global__ __launch_bounds__(256)
void kG2(const __bf16* __restrict__ inp_bf, const __bf16* __restrict__ w1b,
         float* __restrict__ part2)
{
    const int n0 = blockIdx.x * 32;
    const int m0 = blockIdx.y * 32;
    const int ks = blockIdx.z;
    const int t  = threadIdx.x;
    const int wid = t >> 6, l = t & 63;
    const int mbase = (wid >> 1) * 16, nbase = (wid & 1) * 16;

    __shared__ __bf16 Alds[32 * 384];    // 24 KB
    __shared__ __bf16 Blds[32 * 384];    // 24 KB

    // stage: 32 rows x 48 granules = 1536 granules per matrix; 6 per thread
    bf16x8 areg[6], breg[6];
    #pragma unroll
    for (int i = 0; i < 6; ++i) {
        const int c = i * 256 + t;                 // 0..1535
        const int row = c / 48, g = c % 48;
        areg[i] = *(const bf16x8*)(inp_bf + (size_t)(m0 + row) * N1 + ks * 384 + g * 8);
        breg[i] = *(const bf16x8*)(w1b   + (size_t)(n0 + row) * N1 + ks * 384 + g * 8);
    }
    #pragma unroll
    for (int i = 0; i < 6; ++i) {
        const int c = i * 256 + t;
        const int row = c / 48, g = c % 48;
        const int gp = g ^ (row & 7);
        *(bf16x8*)(Alds + row * 384 + gp * 8) = areg[i];
        *(bf16x8*)(Blds + row * 384 + gp * 8) = breg[i];
    }
    __syncthreads();

    fx4 acc0 = {}, acc1 = {};
    const int fr = l & 15, fq = l >> 4;
    const __bf16* Ab = Alds + (mbase + fr) * 384;
    const __bf16* Bb = Blds + (nbase + fr) * 384;
    const int ax = (mbase + fr) & 7, bx = (nbase + fr) & 7;
    #pragma unroll
    for (int s = 0; s < 12; s += 2) {
        bf16x8 a0 = *(const bf16x8*)(Ab + ((s * 4 + fq) ^ ax) * 8);
        bf16x8 b0 = *(const bf16x8*)(Bb + ((s * 4 + fq) ^ bx) * 8);
        acc0 = mfma16(a0, b0, acc0);
        bf16x8 a1 = *(const bf16x8*)(Ab + (((s + 1) * 4 + fq) ^ ax) * 8);
        bf16x8 b1 = *(const bf16x8*)(Bb + (((s + 1) * 4 + fq) ^ bx) * 8);
        acc1 = mfma16(a1, b1, acc1);
    }

    float* dst = part2 + (size_t)ks * P2S;
    const int col  = n0 + nbase + fr;
    const int row0 = m0 + mbase + fq * 4;
    #pragma unroll
    for (int j = 0; j < 4; ++j)
        dst[(size_t)(row0 + j) * N2 + col] = acc0[j] + acc1[j];
}

// ========== kEF: combine 4 partials + redundant BN stats + output ==========
// 16 blocks x 256; thread t computes column-t stats (same f32 add order as output).
__global__ __launch_bounds__(256)
void kEF(const float* __restrict__ part2, const float* __restrict__ b1,
         const float* __restrict__ gamma, const float* __restrict__ beta,
         const float* __restrict__ w2, const float* __restrict__ b2,
         float* __restrict__ out)
{
    __shared__ float s_scale[256];
    __shared__ float s_shift[256];
    const int t = threadIdx.x;

    const float bias = b1[t];
    float sum = 0.f, sq = 0.f;
    #pragma unroll 8
    for (int r = 0; r < 128; ++r) {
        float v = (((part2[r * N2 + t] + part2[P2S + r * N2 + t])
                  + part2[2 * P2S + r * N2 + t]) + part2[3 * P2S + r * N2 + t]) + bias;
        sum += v;
        sq  += v * v;
    }
    const float mu  = sum * (1.0f / 128.0f);
    const float var = sq * (1.0f / 128.0f) - mu * mu;   // biased batch var
    const float rs  = rsqrtf(var + 1e-5f);
    const float sc  = gamma[t] * rs;
    s_scale[t] = sc;
    s_shift[t] = beta[t] - mu * sc;
    __syncthreads();

    const int wv = t >> 6, l = t & 63;
    #pragma unroll
    for (int rr = 0; rr < 2; ++rr) {
        const int b = blockIdx.x * 8 + wv * 2 + rr;
        float acc = 0.f;
        #pragma unroll
        for (int i = 0; i < 4; ++i) {
            const int j = l + i * 64;
            float v = (((part2[b * N2 + j] + part2[P2S + b * N2 + j])
                      + part2[2 * P2S + b * N2 + j]) + part2[3 * P2S + b * N2 + j]) + b1[j];
            float x = v * s_scale[j] + s_shift[j];
            x = fmaxf(x, 0.f);
            acc += x * w2[j];
        }
        #pragma unroll
        for (int off = 32; off; off >>= 1) acc += __shfl_xor(acc, off);
        if (l == 0) out[b] = 1.0f / (1.0f + expf(-(acc + b2[0])));
    }
}

extern "C" void kernel_launch(void* const* d_in, const int* in_sizes, int n_in,
                              void* d_out, int out_size, void* d_ws, size_t ws_size,
                              hipStream_t stream) {
    const int*   sample    = (const int*)  d_in[0];
    const int*   gb        = (const int*)  d_in[1];
    const float* p_feature = (const float*)d_in[2];
    const float* tweet_emb = (const float*)d_in[3];
    const float* desc_emb  = (const float*)d_in[4];
    const float* t_w       = (const float*)d_in[5];
    const float* t_b       = (const float*)d_in[6];
    const float* w1        = (const float*)d_in[7];
    const float* b1        = (const float*)d_in[8];
    const float* gamma     = (const float*)d_in[9];
    const float* beta      = (const float*)d_in[10];
    const float* w2        = (const float*)d_in[11];
    const float* b2        = (const float*)d_in[12];
    float* out = (float*)d_out;

    char* ws = (char*)d_ws;
    __bf16* Abuf   = (__bf16*)(ws + OFF_ABUF);
    __bf16* twb    = (__bf16*)(ws + OFF_TWB);
    __bf16* w1b    = (__bf16*)(ws + OFF_W1B);
    __bf16* inp_bf = (__bf16*)(ws + OFF_INPB);
    float*  part1  = (float*)(ws + OFF_P1);
    float*  part2  = (float*)(ws + OFF_P2);
    int*    uidx   = (int*)  (ws + OFF_UIDX);

    const int n_nodes = in_sizes[1];
    const int scatter_blocks = (n_nodes + 255) / 256;

    kA_prep<<<1152 + scatter_blocks, 256, 0, stream>>>(sample, gb, n_nodes,
        tweet_emb, desc_emb, t_w, w1, Abuf, twb, w1b, uidx);
    kB_gemm1<<<dim3(8, 6, 4), 256, 0, stream>>>(Abuf, twb, part1);
    kC_comb1<<<192, 256, 0, stream>>>(part1, t_b, p_feature, uidx, inp_bf);
    kG2<<<dim3(8, 4, 4), 256, 0, stream>>>(inp_bf, w1b, part2);
    kEF<<<16, 256, 0, stream>>>(part2, b1, gamma, beta, w2, b2, out);
}

// Round 10
// 27.817 us; speedup vs baseline: 1.2285x; 1.1614x over previous
//
#include <hip/hip_runtime.h>
#include <math.h>

#define BB 128
#define HID 512
#define EMB 1024
#define N1 1536
#define N2 256

typedef __attribute__((ext_vector_type(8))) __bf16 bf16x8;
typedef __attribute__((ext_vector_type(4))) __bf16 bf16x4;
typedef __attribute__((ext_vector_type(4))) float fx4;

// ---------------- ws layout (bytes) ----------------
#define OFF_ABUF 0            // [384][1024] bf16   = 786432
#define OFF_TWB  786432       // [512][1024] bf16   = 1048576
#define OFF_W1B  1835008      // [256][1536] bf16   = 786432
#define OFF_INPB 2621440      // [384][512]  bf16   = 393216
#define OFF_P1   3014656      // [4][384][512] f32  = 3145728
#define OFF_P2   6160384      // [4][128][256] f32  = 524288
#define OFF_H    6684672      // [128][256] f32     = 131072
#define OFF_SC   6815744      // [256] f32
#define OFF_SH   6816768      // [256] f32
#define OFF_UIDX 6817792      // [128] i32

__device__ __forceinline__ fx4 mfma16(bf16x8 a, bf16x8 b, fx4 c) {
    return __builtin_amdgcn_mfma_f32_16x16x32_bf16(a, b, c, 0, 0, 0);
}

// LDS tile: [64 rows][64 k] bf16, 16B-granule XOR swizzle: granule g of row r
// lives at physical granule g ^ (r&7).  (T2; read side applies same XOR.)
__device__ __forceinline__ int lds_idx(int row, int g) {
    return row * 64 + ((g ^ (row & 7)) * 8);
}

// ---------------- A: gather + f32->bf16 convert + u_idx scatter ----------------
// blocks 0..383: Abuf row (s*128+b); 384..895: t_w row; 896..1151: w1 row;
// 1152..: u_idx scatter over nodes.
__global__ __launch_bounds__(256)
void kA_prep(const int* __restrict__ sample, const int* __restrict__ gb, int n_nodes,
             const float* __restrict__ tweet_emb, const float* __restrict__ desc_emb,
             const float* __restrict__ t_w, const float* __restrict__ w1,
             __bf16* __restrict__ Abuf, __bf16* __restrict__ twb,
             __bf16* __restrict__ w1b, int* __restrict__ uidx)
{
    const int blk = blockIdx.x;
    const int t   = threadIdx.x;

    if (blk < 384) {
        const int s = blk >> 7, b = blk & 127;
        const int id = sample[b * 3 + s];
        const float* src = (s == 1) ? (tweet_emb + (size_t)id * EMB)
                                    : (desc_emb + (size_t)id * EMB);
        float4 v = *(const float4*)(src + t * 4);
        bf16x4 o = {(__bf16)v.x, (__bf16)v.y, (__bf16)v.z, (__bf16)v.w};
        *(bf16x4*)(Abuf + (size_t)blk * EMB + t * 4) = o;
    } else if (blk < 896) {
        const int r = blk - 384;
        float4 v = *(const float4*)(t_w + (size_t)r * EMB + t * 4);
        bf16x4 o = {(__bf16)v.x, (__bf16)v.y, (__bf16)v.z, (__bf16)v.w};
        *(bf16x4*)(twb + (size_t)r * EMB + t * 4) = o;
    } else if (blk < 1152) {
        const int r = blk - 896;
        for (int i = t; i < 384; i += 256) {
            float4 v = *(const float4*)(w1 + (size_t)r * N1 + i * 4);
            bf16x4 o = {(__bf16)v.x, (__bf16)v.y, (__bf16)v.z, (__bf16)v.w};
            *(bf16x4*)(w1b + (size_t)r * N1 + i * 4) = o;
        }
    } else {
        const int n = (blk - 1152) * 256 + t;
        if (n < n_nodes) {
            const int g = gb[n];
            if (n == 0 || gb[n - 1] != g) uidx[g] = n;
        }
    }
}

// ---------------- B: K1 GEMM  part1[ks][m][n] = Abuf[m][kslice] . twb[n][kslice]
// grid (8 n-tiles, 6 m-tiles, 4 k-splits), 256 threads (4 waves, 32x32 each).
__global__ __launch_bounds__(256)
void kB_gemm1(const __bf16* __restrict__ Abuf, const __bf16* __restrict__ twb,
              float* __restrict__ part1)
{
    const int n0 = blockIdx.x * 64;
    const int m0 = blockIdx.y * 64;
    const int ks = blockIdx.z;
    const int t  = threadIdx.x;
    const int wid = t >> 6, l = t & 63;
    const int mbase = (wid >> 1) * 32, nbase = (wid & 1) * 32;

    __shared__ __bf16 Alds[64 * 64];
    __shared__ __bf16 Blds[64 * 64];

    const int srow = t >> 2;          // staging row 0..63
    const int g0   = (t & 3) * 2;     // granule pair

    fx4 acc[2][2] = {};

    bf16x8 av0, av1, bv0, bv1;
    {
        const int k0 = ks * 256;
        const __bf16* ap = Abuf + (size_t)(m0 + srow) * EMB + k0 + g0 * 8;
        const __bf16* bp = twb  + (size_t)(n0 + srow) * EMB + k0 + g0 * 8;
        av0 = *(const bf16x8*)ap; av1 = *(const bf16x8*)(ap + 8);
        bv0 = *(const bf16x8*)bp; bv1 = *(const bf16x8*)(bp + 8);
    }

    for (int kt = 0; kt < 4; ++kt) {
        __syncthreads();
        *(bf16x8*)&Alds[lds_idx(srow, g0)]     = av0;
        *(bf16x8*)&Alds[lds_idx(srow, g0 + 1)] = av1;
        *(bf16x8*)&Blds[lds_idx(srow, g0)]     = bv0;
        *(bf16x8*)&Blds[lds_idx(srow, g0 + 1)] = bv1;
        __syncthreads();

        if (kt < 3) {
            const int k0 = ks * 256 + (kt + 1) * 64;
            const __bf16* ap = Abuf + (size_t)(m0 + srow) * EMB + k0 + g0 * 8;
            const __bf16* bp = twb  + (size_t)(n0 + srow) * EMB + k0 + g0 * 8;
            av0 = *(const bf16x8*)ap; av1 = *(const bf16x8*)(ap + 8);
            bv0 = *(const bf16x8*)bp; bv1 = *(const bf16x8*)(bp + 8);
        }

        #pragma unroll
        for (int kq = 0; kq < 2; ++kq) {
            const int g = kq * 4 + (l >> 4);
            bf16x8 a0 = *(const bf16x8*)&Alds[lds_idx(mbase +      (l & 15), g)];
            bf16x8 a1 = *(const bf16x8*)&Alds[lds_idx(mbase + 16 + (l & 15), g)];
            bf16x8 b0 = *(const bf16x8*)&Blds[lds_idx(nbase +      (l & 15), g)];
            bf16x8 b1 = *(const bf16x8*)&Blds[lds_idx(nbase + 16 + (l & 15), g)];
            acc[0][0] = mfma16(a0, b0, acc[0][0]);
            acc[0][1] = mfma16(a0, b1, acc[0][1]);
            acc[1][0] = mfma16(a1, b0, acc[1][0]);
            acc[1][1] = mfma16(a1, b1, acc[1][1]);
        }
    }

    float* dst = part1 + (size_t)ks * (384 * 512);
    #pragma unroll
    for (int mi = 0; mi < 2; ++mi)
        #pragma unroll
        for (int ni = 0; ni < 2; ++ni) {
            const int row = m0 + mbase + mi * 16 + (l >> 4) * 4;
            const int col = n0 + nbase + ni * 16 + (l & 15);
            #pragma unroll
            for (int j = 0; j < 4; ++j)
                dst[(size_t)(row + j) * 512 + col] = acc[mi][ni][j];
        }
}

// ---------------- C: combine K1 partials + t_b + p_feature gather -> inp_bf (bf16)
// grid 192 x 256: block = 2 rows of [384][512].
__global__ __launch_bounds__(256)
void kC_comb1(const float* __restrict__ part1, const float* __restrict__ t_b,
              const float* __restrict__ p_feature, const int* __restrict__ uidx,
              __bf16* __restrict__ inp_bf)
{
    const int t = threadIdx.x;
    const int m = blockIdx.x * 2 + (t >> 7);
    const int j0 = (t & 127) * 4;
    const int s = m >> 7, b = m & 127;

    float4 v = *(const float4*)(part1 + (size_t)m * 512 + j0);
    #pragma unroll
    for (int p = 1; p < 4; ++p) {
        float4 q = *(const float4*)(part1 + (size_t)p * (384 * 512) + (size_t)m * 512 + j0);
        v.x += q.x; v.y += q.y; v.z += q.z; v.w += q.w;
    }
    float4 tb = *(const float4*)(t_b + j0);
    v.x += tb.x; v.y += tb.y; v.z += tb.z; v.w += tb.w;
    if (s != 1) {
        const int node = (s == 0) ? uidx[b] : (uidx[b] + 1);
        float4 pf = *(const float4*)(p_feature + (size_t)node * HID + j0);
        v.x += pf.x; v.y += pf.y; v.z += pf.z; v.w += pf.w;
    }
    bf16x4 o = {(__bf16)v.x, (__bf16)v.y, (__bf16)v.z, (__bf16)v.w};
    *(bf16x4*)(inp_bf + (size_t)m * 512 + j0) = o;
}

// ---------------- D: K2 GEMM  part2[ks][b][n] = inp[b][kslice] . w1[n][kslice]
// inp logical [128][1536], physical inp_bf[(k>>9)*128 + b][k&511].
// grid (4 n-tiles, 2 m-tiles, 4 k-splits of 384), 256 threads.
__global__ __launch_bounds__(256)
void kD_gemm2(const __bf16* __restrict__ inp_bf, const __bf16* __restrict__ w1b,
              float* __restrict__ part2)
{
    const int n0 = blockIdx.x * 64;
    const int m0 = blockIdx.y * 64;
    const int ks = blockIdx.z;
    const int t  = threadIdx.x;
    const int wid = t >> 6, l = t & 63;
    const int mbase = (wid >> 1) * 32, nbase = (wid & 1) * 32;

    __shared__ __bf16 Alds[64 * 64];
    __shared__ __bf16 Blds[64 * 64];

    const int srow = t >> 2;
    const int g0   = (t & 3) * 2;

    fx4 acc[2][2] = {};

    bf16x8 av0, av1, bv0, bv1;
    {
        const int k0 = ks * 384;
        const __bf16* ap = inp_bf + (size_t)((k0 >> 9) * 128 + m0 + srow) * HID + (k0 & 511) + g0 * 8;
        const __bf16* bp = w1b + (size_t)(n0 + srow) * N1 + k0 + g0 * 8;
        av0 = *(const bf16x8*)ap; av1 = *(const bf16x8*)(ap + 8);
        bv0 = *(const bf16x8*)bp; bv1 = *(const bf16x8*)(bp + 8);
    }

    for (int kt = 0; kt < 6; ++kt) {
        __syncthreads();
        *(bf16x8*)&Alds[lds_idx(srow, g0)]     = av0;
        *(bf16x8*)&Alds[lds_idx(srow, g0 + 1)] = av1;
        *(bf16x8*)&Blds[lds_idx(srow, g0)]     = bv0;
        *(bf16x8*)&Blds[lds_idx(srow, g0 + 1)] = bv1;
        __syncthreads();

        if (kt < 5) {
            const int k0 = ks * 384 + (kt + 1) * 64;
            const __bf16* ap = inp_bf + (size_t)((k0 >> 9) * 128 + m0 + srow) * HID + (k0 & 511) + g0 * 8;
            const __bf16* bp = w1b + (size_t)(n0 + srow) * N1 + k0 + g0 * 8;
            av0 = *(const bf16x8*)ap; av1 = *(const bf16x8*)(ap + 8);
            bv0 = *(const bf16x8*)bp; bv1 = *(const bf16x8*)(bp + 8);
        }

        #pragma unroll
        for (int kq = 0; kq < 2; ++kq) {
            const int g = kq * 4 + (l >> 4);
            bf16x8 a0 = *(const bf16x8*)&Alds[lds_idx(mbase +      (l & 15), g)];
            bf16x8 a1 = *(const bf16x8*)&Alds[lds_idx(mbase + 16 + (l & 15), g)];
            bf16x8 b0 = *(const bf16x8*)&Blds[lds_idx(nbase +      (l & 15), g)];
            bf16x8 b1 = *(const bf16x8*)&Blds[lds_idx(nbase + 16 + (l & 15), g)];
            acc[0][0] = mfma16(a0, b0, acc[0][0]);
            acc[0][1] = mfma16(a0, b1, acc[0][1]);
            acc[1][0] = mfma16(a1, b0, acc[1][0]);
            acc[1][1] = mfma16(a1, b1, acc[1][1]);
        }
    }

    float* dst = part2 + (size_t)ks * (128 * 256);
    #pragma unroll
    for (int mi = 0; mi < 2; ++mi)
        #pragma unroll
        for (int ni = 0; ni < 2; ++ni) {
            const int row = m0 + mbase + mi * 16 + (l >> 4) * 4;
            const int col = n0 + nbase + ni * 16 + (l & 15);
            #pragma unroll
            for (int j = 0; j < 4; ++j)
                dst[(size_t)(row + j) * 256 + col] = acc[mi][ni][j];
        }
}

// ---------------- E: combine K2 partials + b1 -> h; BN batch stats -> scale/shift
__global__ __launch_bounds__(256)
void kE_stats(const float* __restrict__ part2, const float* __restrict__ b1,
              const float* __restrict__ gamma, const float* __restrict__ beta,
              float* __restrict__ hbuf, float* __restrict__ scale,
              float* __restrict__ shift)
{
    const int bl = blockIdx.x;
    const int t  = threadIdx.x;
    const int j  = bl * 32 + (t & 31);
    const int q  = t >> 5;

    const float bias = b1[j];
    float sum = 0.f, sq = 0.f;
    for (int i = 0; i < 16; ++i) {
        const int b = q * 16 + i;
        float v = bias;
        #pragma unroll
        for (int p = 0; p < 4; ++p)
            v += part2[(size_t)p * (128 * 256) + b * N2 + j];
        hbuf[b * N2 + j] = v;
        sum += v;
        sq  += v * v;
    }

    __shared__ float s_sum[8][32];
    __shared__ float s_sq[8][32];
    s_sum[q][t & 31] = sum;
    s_sq[q][t & 31]  = sq;
    __syncthreads();

    if (t < 32) {
        float S = 0.f, Q = 0.f;
        #pragma unroll
        for (int q2 = 0; q2 < 8; ++q2) { S += s_sum[q2][t]; Q += s_sq[q2][t]; }
        const float mu  = S * (1.0f / 128.0f);
        const float var = Q * (1.0f / 128.0f) - mu * mu;
        const float rs  = rsqrtf(var + 1e-5f);
        const int jj = bl * 32 + t;
        const float sc = gamma[jj] * rs;
        scale[jj] = sc;
        shift[jj] = beta[jj] - mu * sc;
    }
}

// ---------------- F: normalize+ReLU+dot(w2)+sigmoid ----------------
__global__ __launch_bounds__(256)
void kF_out(const float* __restrict__ hbuf, const float* __restrict__ scale,
            const float* __restrict__ shift, const float* __restrict__ w2,
            const float* __restrict__ b2, float* __restrict__ out)
{
    const int t  = threadIdx.x;
    const int wv = t >> 6;
    const int l  = t & 63;
    const int b0 = blockIdx.x * 8 + wv * 2;

    #pragma unroll
    for (int rr = 0; rr < 2; ++rr) {
        const int b = b0 + rr;
        float acc = 0.f;
        #pragma unroll
        for (int i = 0; i < 4; ++i) {
            const int j = l + i * 64;
            float x = hbuf[b * N2 + j] * scale[j] + shift[j];
            x = fmaxf(x, 0.f);
            acc += x * w2[j];
        }
        #pragma unroll
        for (int off = 32; off; off >>= 1) acc += __shfl_xor(acc, off);
        if (l == 0) out[b] = 1.0f / (1.0f + expf(-(acc + b2[0])));
    }
}

extern "C" void kernel_launch(void* const* d_in, const int* in_sizes, int n_in,
                              void* d_out, int out_size, void* d_ws, size_t ws_size,
                              hipStream_t stream) {
    const int*   sample    = (const int*)  d_in[0];
    const int*   gb        = (const int*)  d_in[1];
    const float* p_feature = (const float*)d_in[2];
    const float* tweet_emb = (const float*)d_in[3];
    const float* desc_emb  = (const float*)d_in[4];
    const float* t_w       = (const float*)d_in[5];
    const float* t_b       = (const float*)d_in[6];
    const float* w1        = (const float*)d_in[7];
    const float* b1        = (const float*)d_in[8];
    const float* gamma     = (const float*)d_in[9];
    const float* beta      = (const float*)d_in[10];
    const float* w2        = (const float*)d_in[11];
    const float* b2        = (const float*)d_in[12];
    float* out = (float*)d_out;

    char* ws = (char*)d_ws;
    __bf16* Abuf   = (__bf16*)(ws + OFF_ABUF);
    __bf16* twb    = (__bf16*)(ws + OFF_TWB);
    __bf16* w1b    = (__bf16*)(ws + OFF_W1B);
    __bf16* inp_bf = (__bf16*)(ws + OFF_INPB);
    float*  part1  = (float*)(ws + OFF_P1);
    float*  part2  = (float*)(ws + OFF_P2);
    float*  hbuf   = (float*)(ws + OFF_H);
    float*  scale  = (float*)(ws + OFF_SC);
    float*  shift  = (float*)(ws + OFF_SH);
    int*    uidx   = (int*)  (ws + OFF_UIDX);

    const int n_nodes = in_sizes[1];
    const int scatter_blocks = (n_nodes + 255) / 256;

    kA_prep<<<1152 + scatter_blocks, 256, 0, stream>>>(sample, gb, n_nodes,
        tweet_emb, desc_emb, t_w, w1, Abuf, twb, w1b, uidx);
    kB_gemm1<<<dim3(8, 6, 4), 256, 0, stream>>>(Abuf, twb, part1);
    kC_comb1<<<192, 256, 0, stream>>>(part1, t_b, p_feature, uidx, inp_bf);
    kD_gemm2<<<dim3(4, 2, 4), 256, 0, stream>>>(inp_bf, w1b, part2);
    kE_stats<<<8, 256, 0, stream>>>(part2, b1, gamma, beta, hbuf, scale, shift);
    kF_out<<<16, 256, 0, stream>>>(hbuf, scale, shift, w2, b2, out);
}